// Round 8
// baseline (1460.192 us; speedup 1.0000x reference)
//
#include <hip/hip_runtime.h>

typedef __bf16 bf16_t;
typedef __bf16 bf16x8 __attribute__((ext_vector_type(8)));
typedef __bf16 bf16x4 __attribute__((ext_vector_type(4)));
typedef float  f32x4  __attribute__((ext_vector_type(4)));

#define T_TOK 8192
#define DIM   1024
#define DFF   4096
#define NEXP  8

__device__ __forceinline__ void gll16(const void* g, void* l) {
    __builtin_amdgcn_global_load_lds(
        (const __attribute__((address_space(1))) char*)g,
        (__attribute__((address_space(3))) char*)l, 16, 0, 0);
}

// ---------------- transpose + convert: src [R][C] f32 -> dst [C][R] bf16, per expert ----------------
__global__ void transpose_cvt_kernel(const float* __restrict__ src, bf16_t* __restrict__ dst,
                                     int R, int C) {
    __shared__ float t[32][33];
    int e = blockIdx.z;
    src += (size_t)e * R * C;
    dst += (size_t)e * R * C;
    int r0 = blockIdx.y * 32, c0 = blockIdx.x * 32;
    int tx = threadIdx.x & 31, ty = threadIdx.x >> 5;
#pragma unroll
    for (int i = 0; i < 4; ++i) {
        int r = ty + i * 8;
        t[r][tx] = src[(size_t)(r0 + r) * C + c0 + tx];
    }
    __syncthreads();
#pragma unroll
    for (int i = 0; i < 4; ++i) {
        int cc = ty + i * 8;
        dst[(size_t)(c0 + cc) * R + r0 + tx] = (bf16_t)t[tx][cc];
    }
}

// ---------------- router: wave per token, f64 accumulation ----------------
__global__ __launch_bounds__(256) void router_kernel(
    const float* __restrict__ x, const float* __restrict__ noise,
    const float* __restrict__ w_route, const float* __restrict__ b_route,
    const float* __restrict__ w_noise, const float* __restrict__ b_noise,
    int* __restrict__ counts, int* __restrict__ lists, float* __restrict__ gate_tok)
{
    int wave = threadIdx.x >> 6;
    int lane = threadIdx.x & 63;
    int t = blockIdx.x * 4 + wave;
    if (t >= T_TOK) return;

    const float* xr = x + (size_t)t * DIM;
    double aR[NEXP], aN[NEXP];
#pragma unroll
    for (int e = 0; e < NEXP; ++e) { aR[e] = 0.0; aN[e] = 0.0; }

#pragma unroll 4
    for (int i = 0; i < 16; ++i) {
        int k = lane + i * 64;
        double xv = (double)xr[k];
        const float4* wr4 = (const float4*)(w_route + (size_t)k * 8);
        const float4* wn4 = (const float4*)(w_noise + (size_t)k * 8);
        float4 r0 = wr4[0], r1 = wr4[1];
        float4 n0 = wn4[0], n1 = wn4[1];
        aR[0] += xv * (double)r0.x; aR[1] += xv * (double)r0.y;
        aR[2] += xv * (double)r0.z; aR[3] += xv * (double)r0.w;
        aR[4] += xv * (double)r1.x; aR[5] += xv * (double)r1.y;
        aR[6] += xv * (double)r1.z; aR[7] += xv * (double)r1.w;
        aN[0] += xv * (double)n0.x; aN[1] += xv * (double)n0.y;
        aN[2] += xv * (double)n0.z; aN[3] += xv * (double)n0.w;
        aN[4] += xv * (double)n1.x; aN[5] += xv * (double)n1.y;
        aN[6] += xv * (double)n1.z; aN[7] += xv * (double)n1.w;
    }
#pragma unroll
    for (int e = 0; e < NEXP; ++e) {
        for (int s = 1; s < 64; s <<= 1) {
            aR[e] += __shfl_xor(aR[e], s);
            aN[e] += __shfl_xor(aN[e], s);
        }
    }
    if (lane == 0) {
        double nv[NEXP];
#pragma unroll
        for (int e = 0; e < NEXP; ++e) {
            double lg = aR[e] + (double)b_route[e];
            double nl = aN[e] + (double)b_noise[e];
            double sp = (nl > 30.0) ? nl : log1p(exp(nl));
            nv[e] = lg + (double)noise[(size_t)t * 8 + e] * sp;
        }
        int i1 = 0;
#pragma unroll
        for (int e = 1; e < NEXP; ++e) if (nv[e] > nv[i1]) i1 = e;
        int i2 = (i1 == 0) ? 1 : 0;
#pragma unroll
        for (int e = 0; e < NEXP; ++e) if (e != i1 && nv[e] > nv[i2]) i2 = e;
        double m = nv[i1];
        double e2 = exp(nv[i2] - m);
        double s = 1.0 + e2;
        gate_tok[2 * t + 0] = (float)(1.0 / s);
        gate_tok[2 * t + 1] = (float)(e2 / s);
        int p1 = atomicAdd(&counts[i1], 1);
        lists[i1 * T_TOK + p1] = 2 * t + 0;
        int p2 = atomicAdd(&counts[i2], 1);
        lists[i2 * T_TOK + p2] = 2 * t + 1;
    }
}

// ---------------- prefix: bases[e] = exclusive prefix sum of counts ----------------
__global__ void prefix_kernel(const int* __restrict__ counts, int* __restrict__ bases) {
    if (threadIdx.x == 0 && blockIdx.x == 0) {
        int s = 0;
#pragma unroll
        for (int e = 0; e < NEXP; ++e) { bases[e] = s; s += counts[e]; }
    }
}

// ---------------- pack A (f32 x -> bf16 packed rows) + inverse map ----------------
__global__ __launch_bounds__(256) void pack_a_kernel(
    const float* __restrict__ x, const int* __restrict__ counts,
    const int* __restrict__ bases, const int* __restrict__ lists,
    bf16_t* __restrict__ Ap, int* __restrict__ inv)
{
    int wave = threadIdx.x >> 6, lane = threadIdx.x & 63;
    int slot = blockIdx.x * 4 + wave;
    int e = slot >> 13;            // / T_TOK
    int pos = slot & (T_TOK - 1);
    if (pos >= counts[e]) return;
    int entry = lists[e * T_TOK + pos];
    int ppos = bases[e] + pos;
    if (lane == 0) inv[entry] = ppos;
    const float4* src = (const float4*)(x + (size_t)(entry >> 1) * DIM);
    bf16x4* dst = (bf16x4*)(Ap + (size_t)ppos * DIM);
#pragma unroll
    for (int j = 0; j < 4; ++j) {
        float4 v = src[lane + j * 64];
        bf16x4 o;
        o[0] = (bf16_t)v.x; o[1] = (bf16_t)v.y; o[2] = (bf16_t)v.z; o[3] = (bf16_t)v.w;
        dst[lane + j * 64] = o;
    }
}

// ---------------- grouped GEMM: 256x256 tile, BK=64, 8 waves, counted-vmcnt dbuf ----------------
// The r6-GEMM2-proven config (best measured: ~275 us, ~500 TF), now for BOTH
// modes: natural (xi,yi,e) grid — no XCD remap (r6's GEMM1 clustering was the
// regression: serialized each expert onto one XCD, no FETCH reduction).
// Static 4-buffer LDS (128 KB, 1 block/CU), raw s_barrier only, counted
// s_waitcnt vmcnt(8): next tile's 8 gll16/wave stay in flight across the
// barrier. 512 MFMA/block/K-tile amortizes latency at depth 1.
// T2 swizzle both-sides (0 conflicts since r2). A-side packed sequential.
// MODE 0: H[base+row] = relu(Ap[base+row] @ w1t^T + b1), K=1024, N=4096
// MODE 1: Yp[base+row] = gate * (H[base+row] @ w2t^T + b2), K=4096, N=1024
template<int K, int MODE>
__global__ __launch_bounds__(512, 2) void moe_gemm_kernel(
    const bf16_t* __restrict__ Asrc, const bf16_t* __restrict__ Wt,
    const float* __restrict__ bias,
    const int* __restrict__ counts, const int* __restrict__ bases,
    const int* __restrict__ lists, const float* __restrict__ gate_tok,
    bf16_t* __restrict__ Hout, float* __restrict__ Yp)
{
    constexpr int N = (MODE == 0) ? DFF : DIM;
    constexpr int NT = K / 64;   // 16 or 64, always even
    int e = blockIdx.z;
    int cnt = counts[e];
    int m0 = blockIdx.x * 256;
    if (m0 >= cnt) return;
    int base = bases[e];
    int n0 = blockIdx.y * 256;
    const int* list = lists + e * T_TOK;
    const bf16_t* W = Wt + (size_t)e * N * K;

    __shared__ __attribute__((aligned(16))) bf16_t Ah0[256 * 64];
    __shared__ __attribute__((aligned(16))) bf16_t Bh0[256 * 64];
    __shared__ __attribute__((aligned(16))) bf16_t Ah1[256 * 64];
    __shared__ __attribute__((aligned(16))) bf16_t Bh1[256 * 64];

    int tid = threadIdx.x;
    int lane = tid & 63;
    int wave = tid >> 6;              // 0..7
    int wr = wave >> 2, wc = wave & 3;

    int kcs = (((lane & 7) ^ (lane >> 3)) << 3);   // swizzled bf16 col offset
    const bf16_t* pA[4];
    const bf16_t* pB[4];
#pragma unroll
    for (int i = 0; i < 4; ++i) {
        int c = wave * 4 + i;            // chunk 0..31 (1KB each, 8 rows)
        int r = c * 8 + (lane >> 3);     // row within 256-row tile
        int ridx = m0 + r; if (ridx > cnt - 1) ridx = cnt - 1;
        pA[i] = Asrc + (size_t)(base + ridx) * K + kcs;
        pB[i] = W + (size_t)(n0 + r) * K + kcs;
    }

    f32x4 acc[8][4];
#pragma unroll
    for (int m = 0; m < 8; ++m)
#pragma unroll
        for (int n = 0; n < 4; ++n)
            acc[m][n] = (f32x4){0.f, 0.f, 0.f, 0.f};

    int g = lane >> 4, ln15 = lane & 15, ln7 = lane & 7;

#define STAGE(An, Bn, k0) do {                                               \
    _Pragma("unroll") for (int i = 0; i < 4; ++i) {                          \
        int c = wave * 4 + i;                                                \
        gll16(pA[i] + (k0), (An) + c * 512);                                 \
        gll16(pB[i] + (k0), (Bn) + c * 512);                                 \
    } } while (0)

#define COMPUTE(Ab, Bb) do {                                                 \
    _Pragma("unroll") for (int kk = 0; kk < 2; ++kk) {                       \
        int sw = (((kk * 4 + g) ^ ln7) << 3);                                \
        bf16x8 b[4];                                                         \
        _Pragma("unroll") for (int n = 0; n < 4; ++n)                        \
            b[n] = *(const bf16x8*)((Bb) + (wc * 64 + n * 16 + ln15) * 64 + sw); \
        _Pragma("unroll") for (int m = 0; m < 8; ++m) {                      \
            bf16x8 a = *(const bf16x8*)((Ab) + (wr * 128 + m * 16 + ln15) * 64 + sw); \
            _Pragma("unroll") for (int n = 0; n < 4; ++n)                    \
                acc[m][n] = __builtin_amdgcn_mfma_f32_16x16x32_bf16(a, b[n], acc[m][n], 0, 0, 0); \
        }                                                                    \
    } } while (0)

#define FENCE() __builtin_amdgcn_sched_barrier(0)
#define WAITV(n) asm volatile("s_waitcnt vmcnt(" #n ")" ::: "memory")

    STAGE(Ah0, Bh0, 0);                     // outstanding: 8

    for (int kt = 0; kt < NT; kt += 2) {
        if (kt + 1 < NT) { STAGE(Ah1, Bh1, (kt + 1) * 64); WAITV(8); }
        else             { WAITV(0); }
        FENCE(); __builtin_amdgcn_s_barrier(); FENCE();
        COMPUTE(Ah0, Bh0);
        FENCE(); __builtin_amdgcn_s_barrier(); FENCE();
        if (kt + 2 < NT) { STAGE(Ah0, Bh0, (kt + 2) * 64); WAITV(8); }
        else             { WAITV(0); }
        FENCE(); __builtin_amdgcn_s_barrier(); FENCE();
        COMPUTE(Ah1, Bh1);
        FENCE(); __builtin_amdgcn_s_barrier(); FENCE();
    }
#undef STAGE
#undef COMPUTE
#undef FENCE
#undef WAITV

    // epilogue
    int l4 = lane >> 4;
    float bs[4];
#pragma unroll
    for (int n = 0; n < 4; ++n)
        bs[n] = bias[e * N + n0 + wc * 64 + n * 16 + ln15];
#pragma unroll
    for (int m = 0; m < 8; ++m) {
#pragma unroll
        for (int j = 0; j < 4; ++j) {
            int grow = m0 + wr * 128 + m * 16 + l4 * 4 + j;
            if (grow >= cnt) continue;
            if constexpr (MODE == 0) {
#pragma unroll
                for (int n = 0; n < 4; ++n) {
                    int gcol = n0 + wc * 64 + n * 16 + ln15;
                    float v = acc[m][n][j] + bs[n];
                    Hout[(size_t)(base + grow) * DFF + gcol] = (bf16_t)fmaxf(v, 0.f);
                }
            } else {
                float gt = gate_tok[list[grow]];
#pragma unroll
                for (int n = 0; n < 4; ++n) {
                    int gcol = n0 + wc * 64 + n * 16 + ln15;
                    Yp[(size_t)(base + grow) * DIM + gcol] = gt * (acc[m][n][j] + bs[n]);
                }
            }
        }
    }
}

// ---------------- combine: out[t] = Yp[inv[2t]] + Yp[inv[2t+1]] ----------------
__global__ __launch_bounds__(256) void combine_kernel(
    const float* __restrict__ Yp, const int* __restrict__ inv,
    float* __restrict__ out)
{
    int t = blockIdx.x;
    int p0 = inv[2 * t], p1 = inv[2 * t + 1];
    const float4* a = (const float4*)(Yp + (size_t)p0 * DIM);
    const float4* b = (const float4*)(Yp + (size_t)p1 * DIM);
    float4* o = (float4*)(out + (size_t)t * DIM);
    int i = threadIdx.x;
    float4 va = a[i], vb = b[i];
    o[i] = make_float4(va.x + vb.x, va.y + vb.y, va.z + vb.z, va.w + vb.w);
}

extern "C" void kernel_launch(void* const* d_in, const int* in_sizes, int n_in,
                              void* d_out, int out_size, void* d_ws, size_t ws_size,
                              hipStream_t stream) {
    const float* x       = (const float*)d_in[0];
    const float* noise   = (const float*)d_in[1];
    const float* w_route = (const float*)d_in[2];
    const float* b_route = (const float*)d_in[3];
    const float* w_noise = (const float*)d_in[4];
    const float* b_noise = (const float*)d_in[5];
    const float* w1      = (const float*)d_in[6];
    const float* b1      = (const float*)d_in[7];
    const float* w2      = (const float*)d_in[8];
    const float* b2      = (const float*)d_in[9];
    float* out = (float*)d_out;

    char* ws = (char*)d_ws;
    size_t off = 0;
    auto alloc = [&](size_t bytes) {
        off = (off + 255) & ~(size_t)255;
        size_t r = off; off += bytes; return r;
    };
    int*    counts   = (int*)   (ws + alloc(32));
    int*    bases    = (int*)   (ws + alloc(32));
    int*    lists    = (int*)   (ws + alloc((size_t)NEXP * T_TOK * 4));
    float*  gate_tok = (float*) (ws + alloc((size_t)T_TOK * 2 * 4));
    int*    inv      = (int*)   (ws + alloc((size_t)T_TOK * 2 * 4));
    bf16_t* w1t      = (bf16_t*)(ws + alloc((size_t)NEXP * DFF * DIM * 2));
    bf16_t* w2t      = (bf16_t*)(ws + alloc((size_t)NEXP * DIM * DFF * 2));
    bf16_t* Ap       = (bf16_t*)(ws + alloc((size_t)T_TOK * 2 * DIM * 2));
    bf16_t* H        = (bf16_t*)(ws + alloc((size_t)T_TOK * 2 * DFF * 2));
    // Yp (64MB f32) aliases w1t (64MB): w1t dead after GEMM1; Yp written by
    // GEMM2, read by combine.
    float*  Yp       = (float*)w1t;
    (void)ws_size; (void)in_sizes; (void)n_in; (void)out_size;

    hipMemsetAsync(counts, 0, 32, stream);

    transpose_cvt_kernel<<<dim3(DFF / 32, DIM / 32, NEXP), 256, 0, stream>>>(w1, w1t, DIM, DFF);
    transpose_cvt_kernel<<<dim3(DIM / 32, DFF / 32, NEXP), 256, 0, stream>>>(w2, w2t, DFF, DIM);

    router_kernel<<<T_TOK / 4, 256, 0, stream>>>(x, noise, w_route, b_route, w_noise, b_noise,
                                                 counts, lists, gate_tok);
    prefix_kernel<<<1, 64, 0, stream>>>(counts, bases);
    pack_a_kernel<<<NEXP * T_TOK / 4, 256, 0, stream>>>(x, counts, bases, lists, Ap, inv);

    moe_gemm_kernel<DIM, 0><<<dim3(32, DFF / 256, NEXP), 512, 0, stream>>>(
        Ap, w1t, b1, counts, bases, lists, gate_tok, H, nullptr);
    moe_gemm_kernel<DFF, 1><<<dim3(32, DIM / 256, NEXP), 512, 0, stream>>>(
        H, w2t, b2, counts, bases, lists, gate_tok, nullptr, Yp);

    combine_kernel<<<T_TOK, 256, 0, stream>>>(Yp, inv, out);
}

// Round 9
// 825.134 us; speedup vs baseline: 1.7696x; 1.7696x over previous
//
#include <hip/hip_runtime.h>

typedef __bf16 bf16_t;
typedef __bf16 bf16x8 __attribute__((ext_vector_type(8)));
typedef __bf16 bf16x4 __attribute__((ext_vector_type(4)));
typedef float  f32x4  __attribute__((ext_vector_type(4)));

#define T_TOK 8192
#define DIM   1024
#define DFF   4096
#define NEXP  8

__device__ __forceinline__ void gll16(const void* g, void* l) {
    __builtin_amdgcn_global_load_lds(
        (const __attribute__((address_space(1))) char*)g,
        (__attribute__((address_space(3))) char*)l, 16, 0, 0);
}

// ---------------- transpose + convert: src [R][C] f32 -> dst [C][R] bf16, per expert ----------------
__global__ void transpose_cvt_kernel(const float* __restrict__ src, bf16_t* __restrict__ dst,
                                     int R, int C) {
    __shared__ float t[32][33];
    int e = blockIdx.z;
    src += (size_t)e * R * C;
    dst += (size_t)e * R * C;
    int r0 = blockIdx.y * 32, c0 = blockIdx.x * 32;
    int tx = threadIdx.x & 31, ty = threadIdx.x >> 5;
#pragma unroll
    for (int i = 0; i < 4; ++i) {
        int r = ty + i * 8;
        t[r][tx] = src[(size_t)(r0 + r) * C + c0 + tx];
    }
    __syncthreads();
#pragma unroll
    for (int i = 0; i < 4; ++i) {
        int cc = ty + i * 8;
        dst[(size_t)(c0 + cc) * R + r0 + tx] = (bf16_t)t[tx][cc];
    }
}

// ---------------- router: wave per token, f64 accumulation ----------------
__global__ __launch_bounds__(256) void router_kernel(
    const float* __restrict__ x, const float* __restrict__ noise,
    const float* __restrict__ w_route, const float* __restrict__ b_route,
    const float* __restrict__ w_noise, const float* __restrict__ b_noise,
    int* __restrict__ counts, int* __restrict__ lists, float* __restrict__ gate_tok)
{
    int wave = threadIdx.x >> 6;
    int lane = threadIdx.x & 63;
    int t = blockIdx.x * 4 + wave;
    if (t >= T_TOK) return;

    const float* xr = x + (size_t)t * DIM;
    double aR[NEXP], aN[NEXP];
#pragma unroll
    for (int e = 0; e < NEXP; ++e) { aR[e] = 0.0; aN[e] = 0.0; }

#pragma unroll 4
    for (int i = 0; i < 16; ++i) {
        int k = lane + i * 64;
        double xv = (double)xr[k];
        const float4* wr4 = (const float4*)(w_route + (size_t)k * 8);
        const float4* wn4 = (const float4*)(w_noise + (size_t)k * 8);
        float4 r0 = wr4[0], r1 = wr4[1];
        float4 n0 = wn4[0], n1 = wn4[1];
        aR[0] += xv * (double)r0.x; aR[1] += xv * (double)r0.y;
        aR[2] += xv * (double)r0.z; aR[3] += xv * (double)r0.w;
        aR[4] += xv * (double)r1.x; aR[5] += xv * (double)r1.y;
        aR[6] += xv * (double)r1.z; aR[7] += xv * (double)r1.w;
        aN[0] += xv * (double)n0.x; aN[1] += xv * (double)n0.y;
        aN[2] += xv * (double)n0.z; aN[3] += xv * (double)n0.w;
        aN[4] += xv * (double)n1.x; aN[5] += xv * (double)n1.y;
        aN[6] += xv * (double)n1.z; aN[7] += xv * (double)n1.w;
    }
#pragma unroll
    for (int e = 0; e < NEXP; ++e) {
        for (int s = 1; s < 64; s <<= 1) {
            aR[e] += __shfl_xor(aR[e], s);
            aN[e] += __shfl_xor(aN[e], s);
        }
    }
    if (lane == 0) {
        double nv[NEXP];
#pragma unroll
        for (int e = 0; e < NEXP; ++e) {
            double lg = aR[e] + (double)b_route[e];
            double nl = aN[e] + (double)b_noise[e];
            double sp = (nl > 30.0) ? nl : log1p(exp(nl));
            nv[e] = lg + (double)noise[(size_t)t * 8 + e] * sp;
        }
        int i1 = 0;
#pragma unroll
        for (int e = 1; e < NEXP; ++e) if (nv[e] > nv[i1]) i1 = e;
        int i2 = (i1 == 0) ? 1 : 0;
#pragma unroll
        for (int e = 0; e < NEXP; ++e) if (e != i1 && nv[e] > nv[i2]) i2 = e;
        double m = nv[i1];
        double e2 = exp(nv[i2] - m);
        double s = 1.0 + e2;
        gate_tok[2 * t + 0] = (float)(1.0 / s);
        gate_tok[2 * t + 1] = (float)(e2 / s);
        int p1 = atomicAdd(&counts[i1], 1);
        lists[i1 * T_TOK + p1] = 2 * t + 0;
        int p2 = atomicAdd(&counts[i2], 1);
        lists[i2 * T_TOK + p2] = 2 * t + 1;
    }
}

// ---------------- prefix: bases[e] = exclusive prefix sum of counts ----------------
__global__ void prefix_kernel(const int* __restrict__ counts, int* __restrict__ bases) {
    if (threadIdx.x == 0 && blockIdx.x == 0) {
        int s = 0;
#pragma unroll
        for (int e = 0; e < NEXP; ++e) { bases[e] = s; s += counts[e]; }
    }
}

// ---------------- pack A (f32 x -> bf16 packed rows) + inverse map ----------------
__global__ __launch_bounds__(256) void pack_a_kernel(
    const float* __restrict__ x, const int* __restrict__ counts,
    const int* __restrict__ bases, const int* __restrict__ lists,
    bf16_t* __restrict__ Ap, int* __restrict__ inv)
{
    int wave = threadIdx.x >> 6, lane = threadIdx.x & 63;
    int slot = blockIdx.x * 4 + wave;
    int e = slot >> 13;            // / T_TOK
    int pos = slot & (T_TOK - 1);
    if (pos >= counts[e]) return;
    int entry = lists[e * T_TOK + pos];
    int ppos = bases[e] + pos;
    if (lane == 0) inv[entry] = ppos;
    const float4* src = (const float4*)(x + (size_t)(entry >> 1) * DIM);
    bf16x4* dst = (bf16x4*)(Ap + (size_t)ppos * DIM);
#pragma unroll
    for (int j = 0; j < 4; ++j) {
        float4 v = src[lane + j * 64];
        bf16x4 o;
        o[0] = (bf16_t)v.x; o[1] = (bf16_t)v.y; o[2] = (bf16_t)v.z; o[3] = (bf16_t)v.w;
        dst[lane + j * 64] = o;
    }
}

// ---------------- grouped GEMM: 256x256 tile, BK=64, 8 waves, counted-vmcnt dbuf ----------------
// XCD EXPERT-CLUSTERING (the r6-GEMM1-measured win, ~275 us): e = wg&7 pins
// each expert to one XCD (round-robin dispatch => wg%8 = XCD). Per-XCD L2
// then holds the expert's A working set (GEMM1: A_e ~4MB fully resident;
// GEMM2: per-K-step slices ~384KB shared by lockstep blocks) and same-XCD
// concurrent blocks share B panels -> loads are L2-hits and the depth-1
// counted-vmcnt pipeline covers the latency. Applied to BOTH modes.
// Static 4-buffer LDS (128 KB, 1 block/CU), raw s_barrier only, counted
// s_waitcnt vmcnt(8): next tile's 8 gll16/wave stay in flight across the
// barrier. T2 swizzle both-sides (0 conflicts since r2). A-side packed.
// MODE 0: H[base+row] = relu(Ap[base+row] @ w1t^T + b1), K=1024, N=4096
// MODE 1: Yp[base+row] = gate * (H[base+row] @ w2t^T + b2), K=4096, N=1024
template<int K, int MODE>
__global__ __launch_bounds__(512, 2) void moe_gemm_kernel(
    const bf16_t* __restrict__ Asrc, const bf16_t* __restrict__ Wt,
    const float* __restrict__ bias,
    const int* __restrict__ counts, const int* __restrict__ bases,
    const int* __restrict__ lists, const float* __restrict__ gate_tok,
    bf16_t* __restrict__ Hout, float* __restrict__ Yp)
{
    constexpr int N = (MODE == 0) ? DFF : DIM;
    constexpr int NT = K / 64;   // 16 or 64, always even
    constexpr int NY = N / 256;  // 16 or 4

    // XCD-clustered decode: wg%8 = XCD = expert; xi fastest within an XCD so
    // concurrent same-XCD blocks share the same B panel.
    int wg = blockIdx.x + 32 * (blockIdx.y + NY * blockIdx.z);
    int e = wg & 7;
    int inner = wg >> 3;
    int xi = inner & 31;
    int yi = inner >> 5;

    int cnt = counts[e];
    int m0 = xi * 256;
    if (m0 >= cnt) return;
    int base = bases[e];
    int n0 = yi * 256;
    const int* list = lists + e * T_TOK;
    const bf16_t* W = Wt + (size_t)e * N * K;

    __shared__ __attribute__((aligned(16))) bf16_t Ah0[256 * 64];
    __shared__ __attribute__((aligned(16))) bf16_t Bh0[256 * 64];
    __shared__ __attribute__((aligned(16))) bf16_t Ah1[256 * 64];
    __shared__ __attribute__((aligned(16))) bf16_t Bh1[256 * 64];

    int tid = threadIdx.x;
    int lane = tid & 63;
    int wave = tid >> 6;              // 0..7
    int wr = wave >> 2, wc = wave & 3;

    int kcs = (((lane & 7) ^ (lane >> 3)) << 3);   // swizzled bf16 col offset
    const bf16_t* pA[4];
    const bf16_t* pB[4];
#pragma unroll
    for (int i = 0; i < 4; ++i) {
        int c = wave * 4 + i;            // chunk 0..31 (1KB each, 8 rows)
        int r = c * 8 + (lane >> 3);     // row within 256-row tile
        int ridx = m0 + r; if (ridx > cnt - 1) ridx = cnt - 1;
        pA[i] = Asrc + (size_t)(base + ridx) * K + kcs;
        pB[i] = W + (size_t)(n0 + r) * K + kcs;
    }

    f32x4 acc[8][4];
#pragma unroll
    for (int m = 0; m < 8; ++m)
#pragma unroll
        for (int n = 0; n < 4; ++n)
            acc[m][n] = (f32x4){0.f, 0.f, 0.f, 0.f};

    int g = lane >> 4, ln15 = lane & 15, ln7 = lane & 7;

#define STAGE(An, Bn, k0) do {                                               \
    _Pragma("unroll") for (int i = 0; i < 4; ++i) {                          \
        int c = wave * 4 + i;                                                \
        gll16(pA[i] + (k0), (An) + c * 512);                                 \
        gll16(pB[i] + (k0), (Bn) + c * 512);                                 \
    } } while (0)

#define COMPUTE(Ab, Bb) do {                                                 \
    _Pragma("unroll") for (int kk = 0; kk < 2; ++kk) {                       \
        int sw = (((kk * 4 + g) ^ ln7) << 3);                                \
        bf16x8 b[4];                                                         \
        _Pragma("unroll") for (int n = 0; n < 4; ++n)                        \
            b[n] = *(const bf16x8*)((Bb) + (wc * 64 + n * 16 + ln15) * 64 + sw); \
        _Pragma("unroll") for (int m = 0; m < 8; ++m) {                      \
            bf16x8 a = *(const bf16x8*)((Ab) + (wr * 128 + m * 16 + ln15) * 64 + sw); \
            _Pragma("unroll") for (int n = 0; n < 4; ++n)                    \
                acc[m][n] = __builtin_amdgcn_mfma_f32_16x16x32_bf16(a, b[n], acc[m][n], 0, 0, 0); \
        }                                                                    \
    } } while (0)

#define FENCE() __builtin_amdgcn_sched_barrier(0)
#define WAITV(n) asm volatile("s_waitcnt vmcnt(" #n ")" ::: "memory")

    STAGE(Ah0, Bh0, 0);                     // outstanding: 8

    for (int kt = 0; kt < NT; kt += 2) {
        if (kt + 1 < NT) { STAGE(Ah1, Bh1, (kt + 1) * 64); WAITV(8); }
        else             { WAITV(0); }
        FENCE(); __builtin_amdgcn_s_barrier(); FENCE();
        COMPUTE(Ah0, Bh0);
        FENCE(); __builtin_amdgcn_s_barrier(); FENCE();
        if (kt + 2 < NT) { STAGE(Ah0, Bh0, (kt + 2) * 64); WAITV(8); }
        else             { WAITV(0); }
        FENCE(); __builtin_amdgcn_s_barrier(); FENCE();
        COMPUTE(Ah1, Bh1);
        FENCE(); __builtin_amdgcn_s_barrier(); FENCE();
    }
#undef STAGE
#undef COMPUTE
#undef FENCE
#undef WAITV

    // epilogue
    int l4 = lane >> 4;
    float bs[4];
#pragma unroll
    for (int n = 0; n < 4; ++n)
        bs[n] = bias[e * N + n0 + wc * 64 + n * 16 + ln15];
#pragma unroll
    for (int m = 0; m < 8; ++m) {
#pragma unroll
        for (int j = 0; j < 4; ++j) {
            int grow = m0 + wr * 128 + m * 16 + l4 * 4 + j;
            if (grow >= cnt) continue;
            if constexpr (MODE == 0) {
#pragma unroll
                for (int n = 0; n < 4; ++n) {
                    int gcol = n0 + wc * 64 + n * 16 + ln15;
                    float v = acc[m][n][j] + bs[n];
                    Hout[(size_t)(base + grow) * DFF + gcol] = (bf16_t)fmaxf(v, 0.f);
                }
            } else {
                float gt = gate_tok[list[grow]];
#pragma unroll
                for (int n = 0; n < 4; ++n) {
                    int gcol = n0 + wc * 64 + n * 16 + ln15;
                    Yp[(size_t)(base + grow) * DIM + gcol] = gt * (acc[m][n][j] + bs[n]);
                }
            }
        }
    }
}

// ---------------- combine: out[t] = Yp[inv[2t]] + Yp[inv[2t+1]] ----------------
__global__ __launch_bounds__(256) void combine_kernel(
    const float* __restrict__ Yp, const int* __restrict__ inv,
    float* __restrict__ out)
{
    int t = blockIdx.x;
    int p0 = inv[2 * t], p1 = inv[2 * t + 1];
    const float4* a = (const float4*)(Yp + (size_t)p0 * DIM);
    const float4* b = (const float4*)(Yp + (size_t)p1 * DIM);
    float4* o = (float4*)(out + (size_t)t * DIM);
    int i = threadIdx.x;
    float4 va = a[i], vb = b[i];
    o[i] = make_float4(va.x + vb.x, va.y + vb.y, va.z + vb.z, va.w + vb.w);
}

extern "C" void kernel_launch(void* const* d_in, const int* in_sizes, int n_in,
                              void* d_out, int out_size, void* d_ws, size_t ws_size,
                              hipStream_t stream) {
    const float* x       = (const float*)d_in[0];
    const float* noise   = (const float*)d_in[1];
    const float* w_route = (const float*)d_in[2];
    const float* b_route = (const float*)d_in[3];
    const float* w_noise = (const float*)d_in[4];
    const float* b_noise = (const float*)d_in[5];
    const float* w1      = (const float*)d_in[6];
    const float* b1      = (const float*)d_in[7];
    const float* w2      = (const float*)d_in[8];
    const float* b2      = (const float*)d_in[9];
    float* out = (float*)d_out;

    char* ws = (char*)d_ws;
    size_t off = 0;
    auto alloc = [&](size_t bytes) {
        off = (off + 255) & ~(size_t)255;
        size_t r = off; off += bytes; return r;
    };
    int*    counts   = (int*)   (ws + alloc(32));
    int*    bases    = (int*)   (ws + alloc(32));
    int*    lists    = (int*)   (ws + alloc((size_t)NEXP * T_TOK * 4));
    float*  gate_tok = (float*) (ws + alloc((size_t)T_TOK * 2 * 4));
    int*    inv      = (int*)   (ws + alloc((size_t)T_TOK * 2 * 4));
    bf16_t* w1t      = (bf16_t*)(ws + alloc((size_t)NEXP * DFF * DIM * 2));
    bf16_t* w2t      = (bf16_t*)(ws + alloc((size_t)NEXP * DIM * DFF * 2));
    bf16_t* Ap       = (bf16_t*)(ws + alloc((size_t)T_TOK * 2 * DIM * 2));
    bf16_t* H        = (bf16_t*)(ws + alloc((size_t)T_TOK * 2 * DFF * 2));
    // Yp (64MB f32) aliases w1t (64MB): w1t dead after GEMM1; Yp written by
    // GEMM2, read by combine.
    float*  Yp       = (float*)w1t;
    (void)ws_size; (void)in_sizes; (void)n_in; (void)out_size;

    hipMemsetAsync(counts, 0, 32, stream);

    transpose_cvt_kernel<<<dim3(DFF / 32, DIM / 32, NEXP), 256, 0, stream>>>(w1, w1t, DIM, DFF);
    transpose_cvt_kernel<<<dim3(DIM / 32, DFF / 32, NEXP), 256, 0, stream>>>(w2, w2t, DFF, DIM);

    router_kernel<<<T_TOK / 4, 256, 0, stream>>>(x, noise, w_route, b_route, w_noise, b_noise,
                                                 counts, lists, gate_tok);
    prefix_kernel<<<1, 64, 0, stream>>>(counts, bases);
    pack_a_kernel<<<NEXP * T_TOK / 4, 256, 0, stream>>>(x, counts, bases, lists, Ap, inv);

    moe_gemm_kernel<DIM, 0><<<dim3(32, DFF / 256, NEXP), 512, 0, stream>>>(
        Ap, w1t, b1, counts, bases, lists, gate_tok, H, nullptr);
    moe_gemm_kernel<DFF, 1><<<dim3(32, DIM / 256, NEXP), 512, 0, stream>>>(
        H, w2t, b2, counts, bases, lists, gate_tok, nullptr, Yp);

    combine_kernel<<<T_TOK, 256, 0, stream>>>(Yp, inv, out);
}

// Round 10
// 781.267 us; speedup vs baseline: 1.8690x; 1.0561x over previous
//
#include <hip/hip_runtime.h>

typedef __bf16 bf16_t;
typedef __bf16 bf16x8 __attribute__((ext_vector_type(8)));
typedef __bf16 bf16x4 __attribute__((ext_vector_type(4)));
typedef float  f32x4  __attribute__((ext_vector_type(4)));

#define T_TOK 8192
#define DIM   1024
#define DFF   4096
#define NEXP  8

__device__ __forceinline__ void gll16(const void* g, void* l) {
    __builtin_amdgcn_global_load_lds(
        (const __attribute__((address_space(1))) char*)g,
        (__attribute__((address_space(3))) char*)l, 16, 0, 0);
}

// ---------------- transpose + convert: src [R][C] f32 -> dst [C][R] bf16, per expert ----------------
// 64x64 tiles, float4 reads, bf16x4 writes (128B/16-lane group), 65-pad LDS
// (2-way bank max on both sides).
__global__ __launch_bounds__(256) void transpose_cvt_kernel(
    const float* __restrict__ src, bf16_t* __restrict__ dst, int R, int C) {
    __shared__ float t[64][65];
    int e = blockIdx.z;
    src += (size_t)e * R * C;
    dst += (size_t)e * R * C;
    int r0 = blockIdx.y * 64, c0 = blockIdx.x * 64;
    int tx = threadIdx.x & 15, ty = threadIdx.x >> 4;   // tx: col4 group, ty: 0..15
#pragma unroll
    for (int i = 0; i < 4; ++i) {
        int r = ty + i * 16;
        float4 v = *(const float4*)&src[(size_t)(r0 + r) * C + c0 + tx * 4];
        t[r][tx * 4 + 0] = v.x; t[r][tx * 4 + 1] = v.y;
        t[r][tx * 4 + 2] = v.z; t[r][tx * 4 + 3] = v.w;
    }
    __syncthreads();
#pragma unroll
    for (int i = 0; i < 4; ++i) {
        int cc = ty + i * 16;      // output row = source col
        int rr = tx * 4;           // output col group = source rows
        bf16x4 o;
        o[0] = (bf16_t)t[rr + 0][cc]; o[1] = (bf16_t)t[rr + 1][cc];
        o[2] = (bf16_t)t[rr + 2][cc]; o[3] = (bf16_t)t[rr + 3][cc];
        *(bf16x4*)&dst[(size_t)(c0 + cc) * R + r0 + rr] = o;
    }
}

// ---------------- router: wave per token, f64 accumulation ----------------
__global__ __launch_bounds__(256) void router_kernel(
    const float* __restrict__ x, const float* __restrict__ noise,
    const float* __restrict__ w_route, const float* __restrict__ b_route,
    const float* __restrict__ w_noise, const float* __restrict__ b_noise,
    int* __restrict__ counts, int* __restrict__ lists, float* __restrict__ gate_tok)
{
    int wave = threadIdx.x >> 6;
    int lane = threadIdx.x & 63;
    int t = blockIdx.x * 4 + wave;
    if (t >= T_TOK) return;

    const float* xr = x + (size_t)t * DIM;
    double aR[NEXP], aN[NEXP];
#pragma unroll
    for (int e = 0; e < NEXP; ++e) { aR[e] = 0.0; aN[e] = 0.0; }

#pragma unroll 4
    for (int i = 0; i < 16; ++i) {
        int k = lane + i * 64;
        double xv = (double)xr[k];
        const float4* wr4 = (const float4*)(w_route + (size_t)k * 8);
        const float4* wn4 = (const float4*)(w_noise + (size_t)k * 8);
        float4 r0 = wr4[0], r1 = wr4[1];
        float4 n0 = wn4[0], n1 = wn4[1];
        aR[0] += xv * (double)r0.x; aR[1] += xv * (double)r0.y;
        aR[2] += xv * (double)r0.z; aR[3] += xv * (double)r0.w;
        aR[4] += xv * (double)r1.x; aR[5] += xv * (double)r1.y;
        aR[6] += xv * (double)r1.z; aR[7] += xv * (double)r1.w;
        aN[0] += xv * (double)n0.x; aN[1] += xv * (double)n0.y;
        aN[2] += xv * (double)n0.z; aN[3] += xv * (double)n0.w;
        aN[4] += xv * (double)n1.x; aN[5] += xv * (double)n1.y;
        aN[6] += xv * (double)n1.z; aN[7] += xv * (double)n1.w;
    }
#pragma unroll
    for (int e = 0; e < NEXP; ++e) {
        for (int s = 1; s < 64; s <<= 1) {
            aR[e] += __shfl_xor(aR[e], s);
            aN[e] += __shfl_xor(aN[e], s);
        }
    }
    if (lane == 0) {
        double nv[NEXP];
#pragma unroll
        for (int e = 0; e < NEXP; ++e) {
            double lg = aR[e] + (double)b_route[e];
            double nl = aN[e] + (double)b_noise[e];
            double sp = (nl > 30.0) ? nl : log1p(exp(nl));
            nv[e] = lg + (double)noise[(size_t)t * 8 + e] * sp;
        }
        int i1 = 0;
#pragma unroll
        for (int e = 1; e < NEXP; ++e) if (nv[e] > nv[i1]) i1 = e;
        int i2 = (i1 == 0) ? 1 : 0;
#pragma unroll
        for (int e = 0; e < NEXP; ++e) if (e != i1 && nv[e] > nv[i2]) i2 = e;
        double m = nv[i1];
        double e2 = exp(nv[i2] - m);
        double s = 1.0 + e2;
        gate_tok[2 * t + 0] = (float)(1.0 / s);
        gate_tok[2 * t + 1] = (float)(e2 / s);
        int p1 = atomicAdd(&counts[i1], 1);
        lists[i1 * T_TOK + p1] = 2 * t + 0;
        int p2 = atomicAdd(&counts[i2], 1);
        lists[i2 * T_TOK + p2] = 2 * t + 1;
    }
}

// ---------------- prefix: bases[e] = exclusive prefix sum of counts ----------------
__global__ void prefix_kernel(const int* __restrict__ counts, int* __restrict__ bases) {
    if (threadIdx.x == 0 && blockIdx.x == 0) {
        int s = 0;
#pragma unroll
        for (int e = 0; e < NEXP; ++e) { bases[e] = s; s += counts[e]; }
    }
}

// ---------------- pack A (f32 x -> bf16 packed rows) + inverse map ----------------
__global__ __launch_bounds__(256) void pack_a_kernel(
    const float* __restrict__ x, const int* __restrict__ counts,
    const int* __restrict__ bases, const int* __restrict__ lists,
    bf16_t* __restrict__ Ap, int* __restrict__ inv)
{
    int wave = threadIdx.x >> 6, lane = threadIdx.x & 63;
    int slot = blockIdx.x * 4 + wave;
    int e = slot >> 13;            // / T_TOK
    int pos = slot & (T_TOK - 1);
    if (pos >= counts[e]) return;
    int entry = lists[e * T_TOK + pos];
    int ppos = bases[e] + pos;
    if (lane == 0) inv[entry] = ppos;
    const float4* src = (const float4*)(x + (size_t)(entry >> 1) * DIM);
    bf16x4* dst = (bf16x4*)(Ap + (size_t)ppos * DIM);
#pragma unroll
    for (int j = 0; j < 4; ++j) {
        float4 v = src[lane + j * 64];
        bf16x4 o;
        o[0] = (bf16_t)v.x; o[1] = (bf16_t)v.y; o[2] = (bf16_t)v.z; o[3] = (bf16_t)v.w;
        dst[lane + j * 64] = o;
    }
}

// ---------------- grouped GEMM: 128x128 tile, BK=64, 4 waves, counted-vmcnt dbuf ----------------
// r5-proven skeleton (64 KB LDS -> 2 blocks/CU co-residency) + r9-proven XCD
// expert-clustering (e = wg&7 pins each expert to one XCD; per-K-step slices
// A<=256KB + B<=128KB stay L2-resident; fetch 295->137MB measured r9).
// Combination rationale: clustering turns misses into ~200-400cyc L2 hits;
// the second resident block fills the remaining WAITV/barrier stalls (the
// thing r9's 1-block/CU config structurally lacked).
// Counted s_waitcnt vmcnt(8): next tile's 8 gll16/wave stay in flight across
// the raw s_barrier. T2 swizzle both-sides (0 conflicts since r2).
// T5: setprio(1) around MFMA clusters (2-block residency gives the CU
// scheduler role diversity to arbitrate).
// MODE 0: H[base+row] = relu(Ap[base+row] @ w1t^T + b1), K=1024, N=4096
// MODE 1: Yp[base+row] = gate * (H[base+row] @ w2t^T + b2), K=4096, N=1024
template<int K, int MODE>
__global__ __launch_bounds__(256) void moe_gemm_kernel(
    const bf16_t* __restrict__ Asrc, const bf16_t* __restrict__ Wt,
    const float* __restrict__ bias,
    const int* __restrict__ counts, const int* __restrict__ bases,
    const int* __restrict__ lists, const float* __restrict__ gate_tok,
    bf16_t* __restrict__ Hout, float* __restrict__ Yp)
{
    constexpr int N = (MODE == 0) ? DFF : DIM;
    constexpr int NT = K / 64;   // 16 or 64, always even
    constexpr int NY = N / 128;  // 32 or 8

    // XCD-clustered decode: wg%8 = XCD = expert; xi fastest so concurrent
    // same-XCD blocks share the yi B-panel and the A K-slice.
    int wg = blockIdx.x + 64 * (blockIdx.y + NY * blockIdx.z);
    int e = wg & 7;
    int inner = wg >> 3;
    int xi = inner & 63;
    int yi = inner >> 6;

    int cnt = counts[e];
    int m0 = xi * 128;
    if (m0 >= cnt) return;
    int base = bases[e];
    int n0 = yi * 128;
    const int* list = lists + e * T_TOK;
    const bf16_t* W = Wt + (size_t)e * N * K;

    __shared__ __attribute__((aligned(16))) bf16_t Ah0[128 * 64];
    __shared__ __attribute__((aligned(16))) bf16_t Bh0[128 * 64];
    __shared__ __attribute__((aligned(16))) bf16_t Ah1[128 * 64];
    __shared__ __attribute__((aligned(16))) bf16_t Bh1[128 * 64];

    int tid = threadIdx.x;
    int lane = tid & 63;
    int wave = tid >> 6;
    int wr = wave >> 1, wc = wave & 1;

    int kcs = (((lane & 7) ^ (lane >> 3)) << 3);   // swizzled bf16 col offset
    const bf16_t* pA[4];
    const bf16_t* pB[4];
#pragma unroll
    for (int i = 0; i < 4; ++i) {
        int c = wave * 4 + i;            // chunk 0..15 (1KB each, 8 rows)
        int r = c * 8 + (lane >> 3);     // row within 128-row tile
        int ridx = m0 + r; if (ridx > cnt - 1) ridx = cnt - 1;
        pA[i] = Asrc + (size_t)(base + ridx) * K + kcs;
        pB[i] = W + (size_t)(n0 + r) * K + kcs;
    }

    f32x4 acc[4][4];
#pragma unroll
    for (int m = 0; m < 4; ++m)
#pragma unroll
        for (int n = 0; n < 4; ++n)
            acc[m][n] = (f32x4){0.f, 0.f, 0.f, 0.f};

    int g = lane >> 4, ln15 = lane & 15, ln7 = lane & 7;

#define STAGE(An, Bn, k0) do {                                               \
    _Pragma("unroll") for (int i = 0; i < 4; ++i) {                          \
        int c = wave * 4 + i;                                                \
        gll16(pA[i] + (k0), (An) + c * 512);                                 \
        gll16(pB[i] + (k0), (Bn) + c * 512);                                 \
    } } while (0)

#define COMPUTE(Ab, Bb) do {                                                 \
    _Pragma("unroll") for (int kk = 0; kk < 2; ++kk) {                       \
        bf16x8 a[4], b[4];                                                   \
        int sw = (((kk * 4 + g) ^ ln7) << 3);                                \
        _Pragma("unroll") for (int n = 0; n < 4; ++n)                        \
            b[n] = *(const bf16x8*)((Bb) + (wc * 64 + n * 16 + ln15) * 64 + sw); \
        _Pragma("unroll") for (int m = 0; m < 4; ++m)                        \
            a[m] = *(const bf16x8*)((Ab) + (wr * 64 + m * 16 + ln15) * 64 + sw); \
        __builtin_amdgcn_s_setprio(1);                                       \
        _Pragma("unroll") for (int m = 0; m < 4; ++m)                        \
            _Pragma("unroll") for (int n = 0; n < 4; ++n)                    \
                acc[m][n] = __builtin_amdgcn_mfma_f32_16x16x32_bf16(a[m], b[n], acc[m][n], 0, 0, 0); \
        __builtin_amdgcn_s_setprio(0);                                       \
    } } while (0)

#define FENCE() __builtin_amdgcn_sched_barrier(0)
#define WAITV(n) asm volatile("s_waitcnt vmcnt(" #n ")" ::: "memory")

    STAGE(Ah0, Bh0, 0);                     // outstanding: 8

    for (int kt = 0; kt < NT; kt += 2) {
        if (kt + 1 < NT) { STAGE(Ah1, Bh1, (kt + 1) * 64); WAITV(8); }
        else             { WAITV(0); }
        FENCE(); __builtin_amdgcn_s_barrier(); FENCE();
        COMPUTE(Ah0, Bh0);
        FENCE(); __builtin_amdgcn_s_barrier(); FENCE();
        if (kt + 2 < NT) { STAGE(Ah0, Bh0, (kt + 2) * 64); WAITV(8); }
        else             { WAITV(0); }
        FENCE(); __builtin_amdgcn_s_barrier(); FENCE();
        COMPUTE(Ah1, Bh1);
        FENCE(); __builtin_amdgcn_s_barrier(); FENCE();
    }
#undef STAGE
#undef COMPUTE
#undef FENCE
#undef WAITV

    // epilogue
    int l4 = lane >> 4;
    float bs[4];
#pragma unroll
    for (int n = 0; n < 4; ++n)
        bs[n] = bias[e * N + n0 + wc * 64 + n * 16 + ln15];
#pragma unroll
    for (int m = 0; m < 4; ++m) {
#pragma unroll
        for (int j = 0; j < 4; ++j) {
            int grow = m0 + wr * 64 + m * 16 + l4 * 4 + j;
            if (grow >= cnt) continue;
            if constexpr (MODE == 0) {
#pragma unroll
                for (int n = 0; n < 4; ++n) {
                    int gcol = n0 + wc * 64 + n * 16 + ln15;
                    float v = acc[m][n][j] + bs[n];
                    Hout[(size_t)(base + grow) * DFF + gcol] = (bf16_t)fmaxf(v, 0.f);
                }
            } else {
                float gt = gate_tok[list[grow]];
#pragma unroll
                for (int n = 0; n < 4; ++n) {
                    int gcol = n0 + wc * 64 + n * 16 + ln15;
                    Yp[(size_t)(base + grow) * DIM + gcol] = gt * (acc[m][n][j] + bs[n]);
                }
            }
        }
    }
}

// ---------------- combine: out[t] = Yp[inv[2t]] + Yp[inv[2t+1]] ----------------
__global__ __launch_bounds__(256) void combine_kernel(
    const float* __restrict__ Yp, const int* __restrict__ inv,
    float* __restrict__ out)
{
    int t = blockIdx.x;
    int p0 = inv[2 * t], p1 = inv[2 * t + 1];
    const float4* a = (const float4*)(Yp + (size_t)p0 * DIM);
    const float4* b = (const float4*)(Yp + (size_t)p1 * DIM);
    float4* o = (float4*)(out + (size_t)t * DIM);
    int i = threadIdx.x;
    float4 va = a[i], vb = b[i];
    o[i] = make_float4(va.x + vb.x, va.y + vb.y, va.z + vb.z, va.w + vb.w);
}

extern "C" void kernel_launch(void* const* d_in, const int* in_sizes, int n_in,
                              void* d_out, int out_size, void* d_ws, size_t ws_size,
                              hipStream_t stream) {
    const float* x       = (const float*)d_in[0];
    const float* noise   = (const float*)d_in[1];
    const float* w_route = (const float*)d_in[2];
    const float* b_route = (const float*)d_in[3];
    const float* w_noise = (const float*)d_in[4];
    const float* b_noise = (const float*)d_in[5];
    const float* w1      = (const float*)d_in[6];
    const float* b1      = (const float*)d_in[7];
    const float* w2      = (const float*)d_in[8];
    const float* b2      = (const float*)d_in[9];
    float* out = (float*)d_out;

    char* ws = (char*)d_ws;
    size_t off = 0;
    auto alloc = [&](size_t bytes) {
        off = (off + 255) & ~(size_t)255;
        size_t r = off; off += bytes; return r;
    };
    int*    counts   = (int*)   (ws + alloc(32));
    int*    bases    = (int*)   (ws + alloc(32));
    int*    lists    = (int*)   (ws + alloc((size_t)NEXP * T_TOK * 4));
    float*  gate_tok = (float*) (ws + alloc((size_t)T_TOK * 2 * 4));
    int*    inv      = (int*)   (ws + alloc((size_t)T_TOK * 2 * 4));
    bf16_t* w1t      = (bf16_t*)(ws + alloc((size_t)NEXP * DFF * DIM * 2));
    bf16_t* w2t      = (bf16_t*)(ws + alloc((size_t)NEXP * DIM * DFF * 2));
    bf16_t* Ap       = (bf16_t*)(ws + alloc((size_t)T_TOK * 2 * DIM * 2));
    bf16_t* H        = (bf16_t*)(ws + alloc((size_t)T_TOK * 2 * DFF * 2));
    // Yp (64MB f32) aliases w1t (64MB): w1t dead after GEMM1; Yp written by
    // GEMM2, read by combine.
    float*  Yp       = (float*)w1t;
    (void)ws_size; (void)in_sizes; (void)n_in; (void)out_size;

    hipMemsetAsync(counts, 0, 32, stream);

    transpose_cvt_kernel<<<dim3(DFF / 64, DIM / 64, NEXP), 256, 0, stream>>>(w1, w1t, DIM, DFF);
    transpose_cvt_kernel<<<dim3(DIM / 64, DFF / 64, NEXP), 256, 0, stream>>>(w2, w2t, DFF, DIM);

    router_kernel<<<T_TOK / 4, 256, 0, stream>>>(x, noise, w_route, b_route, w_noise, b_noise,
                                                 counts, lists, gate_tok);
    prefix_kernel<<<1, 64, 0, stream>>>(counts, bases);
    pack_a_kernel<<<NEXP * T_TOK / 4, 256, 0, stream>>>(x, counts, bases, lists, Ap, inv);

    moe_gemm_kernel<DIM, 0><<<dim3(64, DFF / 128, NEXP), 256, 0, stream>>>(
        Ap, w1t, b1, counts, bases, lists, gate_tok, H, nullptr);
    moe_gemm_kernel<DFF, 1><<<dim3(64, DIM / 128, NEXP), 256, 0, stream>>>(
        H, w2t, b2, counts, bases, lists, gate_tok, nullptr, Yp);

    combine_kernel<<<T_TOK, 256, 0, stream>>>(Yp, inv, out);
}

// Round 11
// 780.162 us; speedup vs baseline: 1.8717x; 1.0014x over previous
//
#include <hip/hip_runtime.h>

typedef __bf16 bf16_t;
typedef __bf16 bf16x8 __attribute__((ext_vector_type(8)));
typedef __bf16 bf16x4 __attribute__((ext_vector_type(4)));
typedef float  f32x4  __attribute__((ext_vector_type(4)));

#define T_TOK 8192
#define DIM   1024
#define DFF   4096
#define NEXP  8

__device__ __forceinline__ void gll16(const void* g, void* l) {
    __builtin_amdgcn_global_load_lds(
        (const __attribute__((address_space(1))) char*)g,
        (__attribute__((address_space(3))) char*)l, 16, 0, 0);
}

// ---------------- transpose + convert: src [R][C] f32 -> dst [C][R] bf16, per expert ----------------
// 64x64 tile. Read: f32x4/lane (16 lanes = 256B row segment). LDS [64][65]
// (write banks 2-way, read banks (8rr+j+cc)%32 2-way — both free).
// Write: bf16x8 = 16B/lane; lanes 0..7 cover 128B contiguous of one out-row.
__global__ __launch_bounds__(256) void transpose_cvt_kernel(
    const float* __restrict__ src, bf16_t* __restrict__ dst, int R, int C) {
    __shared__ float t[64][65];
    int e = blockIdx.z;
    src += (size_t)e * R * C;
    dst += (size_t)e * R * C;
    int r0 = blockIdx.y * 64, c0 = blockIdx.x * 64;
    int tid = threadIdx.x;
    {
        int cg = tid & 15, r = tid >> 4;          // cg: 4-col group, r: 0..15
#pragma unroll
        for (int i = 0; i < 4; ++i) {
            int rr = r + i * 16;
            float4 v = *(const float4*)&src[(size_t)(r0 + rr) * C + c0 + cg * 4];
            t[rr][cg * 4 + 0] = v.x; t[rr][cg * 4 + 1] = v.y;
            t[rr][cg * 4 + 2] = v.z; t[rr][cg * 4 + 3] = v.w;
        }
    }
    __syncthreads();
    {
        int rr = tid & 7, c = tid >> 3;           // rr: 8-row group, c: 0..31
#pragma unroll
        for (int i = 0; i < 2; ++i) {
            int cc = c + i * 32;                  // out-row = source col
            bf16x8 o;
#pragma unroll
            for (int j = 0; j < 8; ++j) o[j] = (bf16_t)t[rr * 8 + j][cc];
            *(bf16x8*)&dst[(size_t)(c0 + cc) * R + r0 + rr * 8] = o;
        }
    }
}

// ---------------- router: wave per token, f64 accumulation ----------------
__global__ __launch_bounds__(256) void router_kernel(
    const float* __restrict__ x, const float* __restrict__ noise,
    const float* __restrict__ w_route, const float* __restrict__ b_route,
    const float* __restrict__ w_noise, const float* __restrict__ b_noise,
    int* __restrict__ counts, int* __restrict__ lists, float* __restrict__ gate_tok)
{
    int wave = threadIdx.x >> 6;
    int lane = threadIdx.x & 63;
    int t = blockIdx.x * 4 + wave;
    if (t >= T_TOK) return;

    const float* xr = x + (size_t)t * DIM;
    double aR[NEXP], aN[NEXP];
#pragma unroll
    for (int e = 0; e < NEXP; ++e) { aR[e] = 0.0; aN[e] = 0.0; }

#pragma unroll 4
    for (int i = 0; i < 16; ++i) {
        int k = lane + i * 64;
        double xv = (double)xr[k];
        const float4* wr4 = (const float4*)(w_route + (size_t)k * 8);
        const float4* wn4 = (const float4*)(w_noise + (size_t)k * 8);
        float4 r0 = wr4[0], r1 = wr4[1];
        float4 n0 = wn4[0], n1 = wn4[1];
        aR[0] += xv * (double)r0.x; aR[1] += xv * (double)r0.y;
        aR[2] += xv * (double)r0.z; aR[3] += xv * (double)r0.w;
        aR[4] += xv * (double)r1.x; aR[5] += xv * (double)r1.y;
        aR[6] += xv * (double)r1.z; aR[7] += xv * (double)r1.w;
        aN[0] += xv * (double)n0.x; aN[1] += xv * (double)n0.y;
        aN[2] += xv * (double)n0.z; aN[3] += xv * (double)n0.w;
        aN[4] += xv * (double)n1.x; aN[5] += xv * (double)n1.y;
        aN[6] += xv * (double)n1.z; aN[7] += xv * (double)n1.w;
    }
#pragma unroll
    for (int e = 0; e < NEXP; ++e) {
        for (int s = 1; s < 64; s <<= 1) {
            aR[e] += __shfl_xor(aR[e], s);
            aN[e] += __shfl_xor(aN[e], s);
        }
    }
    if (lane == 0) {
        double nv[NEXP];
#pragma unroll
        for (int e = 0; e < NEXP; ++e) {
            double lg = aR[e] + (double)b_route[e];
            double nl = aN[e] + (double)b_noise[e];
            double sp = (nl > 30.0) ? nl : log1p(exp(nl));
            nv[e] = lg + (double)noise[(size_t)t * 8 + e] * sp;
        }
        int i1 = 0;
#pragma unroll
        for (int e = 1; e < NEXP; ++e) if (nv[e] > nv[i1]) i1 = e;
        int i2 = (i1 == 0) ? 1 : 0;
#pragma unroll
        for (int e = 0; e < NEXP; ++e) if (e != i1 && nv[e] > nv[i2]) i2 = e;
        double m = nv[i1];
        double e2 = exp(nv[i2] - m);
        double s = 1.0 + e2;
        gate_tok[2 * t + 0] = (float)(1.0 / s);
        gate_tok[2 * t + 1] = (float)(e2 / s);
        int p1 = atomicAdd(&counts[i1], 1);
        lists[i1 * T_TOK + p1] = 2 * t + 0;
        int p2 = atomicAdd(&counts[i2], 1);
        lists[i2 * T_TOK + p2] = 2 * t + 1;
    }
}

// ---------------- prefix: bases[e] = exclusive prefix sum of counts ----------------
__global__ void prefix_kernel(const int* __restrict__ counts, int* __restrict__ bases) {
    if (threadIdx.x == 0 && blockIdx.x == 0) {
        int s = 0;
#pragma unroll
        for (int e = 0; e < NEXP; ++e) { bases[e] = s; s += counts[e]; }
    }
}

// ---------------- pack A: flat over the 16384 packed rows (total = 2*T_TOK always) ----------------
__global__ __launch_bounds__(256) void pack_a_kernel(
    const float* __restrict__ x, const int* __restrict__ bases,
    const int* __restrict__ lists, bf16_t* __restrict__ Ap, int* __restrict__ inv)
{
    int wave = threadIdx.x >> 6, lane = threadIdx.x & 63;
    int p = blockIdx.x * 4 + wave;             // packed row 0..16383
    int e = 0;
#pragma unroll
    for (int i = 1; i < NEXP; ++i) e += (p >= bases[i]);
    int pos = p - bases[e];
    int entry = lists[e * T_TOK + pos];
    if (lane == 0) inv[entry] = p;
    const float4* src = (const float4*)(x + (size_t)(entry >> 1) * DIM);
    bf16x4* dst = (bf16x4*)(Ap + (size_t)p * DIM);
#pragma unroll
    for (int j = 0; j < 4; ++j) {
        float4 v = src[lane + j * 64];
        bf16x4 o;
        o[0] = (bf16_t)v.x; o[1] = (bf16_t)v.y; o[2] = (bf16_t)v.z; o[3] = (bf16_t)v.w;
        dst[lane + j * 64] = o;
    }
}

// ---------------- grouped GEMM: 128x128 tile, BK=64, 4 waves, counted-vmcnt dbuf ----------------
// r10 proven (239us/GEMM): 64KB LDS -> 2 blocks/CU + XCD expert-clustering
// (e = wg&7) + counted s_waitcnt vmcnt(8) + T2 swizzle + T5 setprio. UNCHANGED.
template<int K, int MODE>
__global__ __launch_bounds__(256) void moe_gemm_kernel(
    const bf16_t* __restrict__ Asrc, const bf16_t* __restrict__ Wt,
    const float* __restrict__ bias,
    const int* __restrict__ counts, const int* __restrict__ bases,
    const int* __restrict__ lists, const float* __restrict__ gate_tok,
    bf16_t* __restrict__ Hout, float* __restrict__ Yp)
{
    constexpr int N = (MODE == 0) ? DFF : DIM;
    constexpr int NT = K / 64;
    constexpr int NY = N / 128;

    int wg = blockIdx.x + 64 * (blockIdx.y + NY * blockIdx.z);
    int e = wg & 7;
    int inner = wg >> 3;
    int xi = inner & 63;
    int yi = inner >> 6;

    int cnt = counts[e];
    int m0 = xi * 128;
    if (m0 >= cnt) return;
    int base = bases[e];
    int n0 = yi * 128;
    const int* list = lists + e * T_TOK;
    const bf16_t* W = Wt + (size_t)e * N * K;

    __shared__ __attribute__((aligned(16))) bf16_t Ah0[128 * 64];
    __shared__ __attribute__((aligned(16))) bf16_t Bh0[128 * 64];
    __shared__ __attribute__((aligned(16))) bf16_t Ah1[128 * 64];
    __shared__ __attribute__((aligned(16))) bf16_t Bh1[128 * 64];

    int tid = threadIdx.x;
    int lane = tid & 63;
    int wave = tid >> 6;
    int wr = wave >> 1, wc = wave & 1;

    int kcs = (((lane & 7) ^ (lane >> 3)) << 3);
    const bf16_t* pA[4];
    const bf16_t* pB[4];
#pragma unroll
    for (int i = 0; i < 4; ++i) {
        int c = wave * 4 + i;
        int r = c * 8 + (lane >> 3);
        int ridx = m0 + r; if (ridx > cnt - 1) ridx = cnt - 1;
        pA[i] = Asrc + (size_t)(base + ridx) * K + kcs;
        pB[i] = W + (size_t)(n0 + r) * K + kcs;
    }

    f32x4 acc[4][4];
#pragma unroll
    for (int m = 0; m < 4; ++m)
#pragma unroll
        for (int n = 0; n < 4; ++n)
            acc[m][n] = (f32x4){0.f, 0.f, 0.f, 0.f};

    int g = lane >> 4, ln15 = lane & 15, ln7 = lane & 7;

#define STAGE(An, Bn, k0) do {                                               \
    _Pragma("unroll") for (int i = 0; i < 4; ++i) {                          \
        int c = wave * 4 + i;                                                \
        gll16(pA[i] + (k0), (An) + c * 512);                                 \
        gll16(pB[i] + (k0), (Bn) + c * 512);                                 \
    } } while (0)

#define COMPUTE(Ab, Bb) do {                                                 \
    _Pragma("unroll") for (int kk = 0; kk < 2; ++kk) {                       \
        bf16x8 a[4], b[4];                                                   \
        int sw = (((kk * 4 + g) ^ ln7) << 3);                                \
        _Pragma("unroll") for (int n = 0; n < 4; ++n)                        \
            b[n] = *(const bf16x8*)((Bb) + (wc * 64 + n * 16 + ln15) * 64 + sw); \
        _Pragma("unroll") for (int m = 0; m < 4; ++m)                        \
            a[m] = *(const bf16x8*)((Ab) + (wr * 64 + m * 16 + ln15) * 64 + sw); \
        __builtin_amdgcn_s_setprio(1);                                       \
        _Pragma("unroll") for (int m = 0; m < 4; ++m)                        \
            _Pragma("unroll") for (int n = 0; n < 4; ++n)                    \
                acc[m][n] = __builtin_amdgcn_mfma_f32_16x16x32_bf16(a[m], b[n], acc[m][n], 0, 0, 0); \
        __builtin_amdgcn_s_setprio(0);                                       \
    } } while (0)

#define FENCE() __builtin_amdgcn_sched_barrier(0)
#define WAITV(n) asm volatile("s_waitcnt vmcnt(" #n ")" ::: "memory")

    STAGE(Ah0, Bh0, 0);

    for (int kt = 0; kt < NT; kt += 2) {
        if (kt + 1 < NT) { STAGE(Ah1, Bh1, (kt + 1) * 64); WAITV(8); }
        else             { WAITV(0); }
        FENCE(); __builtin_amdgcn_s_barrier(); FENCE();
        COMPUTE(Ah0, Bh0);
        FENCE(); __builtin_amdgcn_s_barrier(); FENCE();
        if (kt + 2 < NT) { STAGE(Ah0, Bh0, (kt + 2) * 64); WAITV(8); }
        else             { WAITV(0); }
        FENCE(); __builtin_amdgcn_s_barrier(); FENCE();
        COMPUTE(Ah1, Bh1);
        FENCE(); __builtin_amdgcn_s_barrier(); FENCE();
    }
#undef STAGE
#undef COMPUTE
#undef FENCE
#undef WAITV

    int l4 = lane >> 4;
    float bs[4];
#pragma unroll
    for (int n = 0; n < 4; ++n)
        bs[n] = bias[e * N + n0 + wc * 64 + n * 16 + ln15];
#pragma unroll
    for (int m = 0; m < 4; ++m) {
#pragma unroll
        for (int j = 0; j < 4; ++j) {
            int grow = m0 + wr * 64 + m * 16 + l4 * 4 + j;
            if (grow >= cnt) continue;
            if constexpr (MODE == 0) {
#pragma unroll
                for (int n = 0; n < 4; ++n) {
                    int gcol = n0 + wc * 64 + n * 16 + ln15;
                    float v = acc[m][n][j] + bs[n];
                    Hout[(size_t)(base + grow) * DFF + gcol] = (bf16_t)fmaxf(v, 0.f);
                }
            } else {
                float gt = gate_tok[list[grow]];
#pragma unroll
                for (int n = 0; n < 4; ++n) {
                    int gcol = n0 + wc * 64 + n * 16 + ln15;
                    Yp[(size_t)(base + grow) * DIM + gcol] = gt * (acc[m][n][j] + bs[n]);
                }
            }
        }
    }
}

// ---------------- combine: out[t] = Yp[inv[2t]] + Yp[inv[2t+1]], 2 rows/block ----------------
__global__ __launch_bounds__(256) void combine_kernel(
    const float* __restrict__ Yp, const int* __restrict__ inv,
    float* __restrict__ out)
{
#pragma unroll
    for (int q = 0; q < 2; ++q) {
        int t = blockIdx.x * 2 + q;
        int p0 = inv[2 * t], p1 = inv[2 * t + 1];
        const float4* a = (const float4*)(Yp + (size_t)p0 * DIM);
        const float4* b = (const float4*)(Yp + (size_t)p1 * DIM);
        float4* o = (float4*)(out + (size_t)t * DIM);
        int i = threadIdx.x;
        float4 va = a[i], vb = b[i];
        o[i] = make_float4(va.x + vb.x, va.y + vb.y, va.z + vb.z, va.w + vb.w);
    }
}

extern "C" void kernel_launch(void* const* d_in, const int* in_sizes, int n_in,
                              void* d_out, int out_size, void* d_ws, size_t ws_size,
                              hipStream_t stream) {
    const float* x       = (const float*)d_in[0];
    const float* noise   = (const float*)d_in[1];
    const float* w_route = (const float*)d_in[2];
    const float* b_route = (const float*)d_in[3];
    const float* w_noise = (const float*)d_in[4];
    const float* b_noise = (const float*)d_in[5];
    const float* w1      = (const float*)d_in[6];
    const float* b1      = (const float*)d_in[7];
    const float* w2      = (const float*)d_in[8];
    const float* b2      = (const float*)d_in[9];
    float* out = (float*)d_out;

    char* ws = (char*)d_ws;
    size_t off = 0;
    auto alloc = [&](size_t bytes) {
        off = (off + 255) & ~(size_t)255;
        size_t r = off; off += bytes; return r;
    };
    int*    counts   = (int*)   (ws + alloc(32));
    int*    bases    = (int*)   (ws + alloc(32));
    int*    lists    = (int*)   (ws + alloc((size_t)NEXP * T_TOK * 4));
    float*  gate_tok = (float*) (ws + alloc((size_t)T_TOK * 2 * 4));
    int*    inv      = (int*)   (ws + alloc((size_t)T_TOK * 2 * 4));
    bf16_t* w1t      = (bf16_t*)(ws + alloc((size_t)NEXP * DFF * DIM * 2));
    bf16_t* w2t      = (bf16_t*)(ws + alloc((size_t)NEXP * DIM * DFF * 2));
    bf16_t* Ap       = (bf16_t*)(ws + alloc((size_t)T_TOK * 2 * DIM * 2));
    bf16_t* H        = (bf16_t*)(ws + alloc((size_t)T_TOK * 2 * DFF * 2));
    // Yp (64MB f32) aliases w1t (64MB): w1t dead after GEMM1; Yp written by
    // GEMM2, read by combine.
    float*  Yp       = (float*)w1t;
    (void)ws_size; (void)in_sizes; (void)n_in; (void)out_size;

    hipMemsetAsync(counts, 0, 32, stream);

    transpose_cvt_kernel<<<dim3(DFF / 64, DIM / 64, NEXP), 256, 0, stream>>>(w1, w1t, DIM, DFF);
    transpose_cvt_kernel<<<dim3(DIM / 64, DFF / 64, NEXP), 256, 0, stream>>>(w2, w2t, DFF, DIM);

    router_kernel<<<T_TOK / 4, 256, 0, stream>>>(x, noise, w_route, b_route, w_noise, b_noise,
                                                 counts, lists, gate_tok);
    prefix_kernel<<<1, 64, 0, stream>>>(counts, bases);
    pack_a_kernel<<<T_TOK * 2 / 4, 256, 0, stream>>>(x, bases, lists, Ap, inv);

    moe_gemm_kernel<DIM, 0><<<dim3(64, DFF / 128, NEXP), 256, 0, stream>>>(
        Ap, w1t, b1, counts, bases, lists, gate_tok, H, nullptr);
    moe_gemm_kernel<DFF, 1><<<dim3(64, DIM / 128, NEXP), 256, 0, stream>>>(
        H, w2t, b2, counts, bases, lists, gate_tok, nullptr, Yp);

    combine_kernel<<<T_TOK / 2, 256, 0, stream>>>(Yp, inv, out);
}